// Round 8
// baseline (316.295 us; speedup 1.0000x reference)
//
#include <hip/hip_runtime.h>
#include <math.h>

// Shape: B=16, C=256, H=W=128, HW=16384. x = 256 MiB fp32.
// Measured facts:
//  - L3 reuse across passes: none. Pure-HBM op; 768 MiB mandatory traffic.
//  - Device-scope atomic/fence fusion: catastrophic (+355 µs). Never.
//  - nt-load neutral; nt-store kept for the write stream.
//  - stats/scale micro-tuning (batch depth, unroll): all neutral — streams
//    run at 93-95% of their measured ceilings already.
// Structure (this round): 2 kernels.
//  K1 stats: per (b,c) block -> mean, max, std(ddof=1) -> u[B][C][3]
//  K2 gate_scale: per (b,c) block -> issue 16 x-loads into regs FIRST, then
//     (hidden under load latency / other waves' streaming) stage u[b] in LDS,
//     rank-select median of 768, compute own channel's conv+BN+sigmoid gate,
//     then multiply + nt-store. Kills the middle kernel + one launch gap.

typedef float fvec4 __attribute__((ext_vector_type(4)));

__global__ __launch_bounds__(256) void stats_kernel(
        const float* __restrict__ x, float* __restrict__ u, int HW) {
    const int bc  = blockIdx.x;
    const int tid = threadIdx.x;
    const float4* __restrict__ x4 =
        (const float4*)(x + (size_t)bc * (size_t)HW);
    const int n4 = HW >> 2;

    float s0 = 0.f, q0 = 0.f, m0 = -INFINITY;
    float s1 = 0.f, q1 = 0.f, m1 = -INFINITY;
    float s2 = 0.f, q2 = 0.f, m2 = -INFINITY;
    float s3 = 0.f, q3 = 0.f, m3 = -INFINITY;

    if (n4 == 4096) {
        #pragma unroll
        for (int half = 0; half < 2; ++half) {
            float4 r[8];
            const int bi = tid + half * 2048;
            #pragma unroll
            for (int k = 0; k < 8; ++k) r[k] = x4[bi + k * 256];
            #pragma unroll
            for (int k = 0; k < 8; k += 4) {
                float4 a = r[k], b = r[k + 1], c = r[k + 2], d = r[k + 3];
                s0 += (a.x + a.y) + (a.z + a.w);
                q0 += (a.x * a.x + a.y * a.y) + (a.z * a.z + a.w * a.w);
                m0 = fmaxf(m0, fmaxf(fmaxf(a.x, a.y), fmaxf(a.z, a.w)));
                s1 += (b.x + b.y) + (b.z + b.w);
                q1 += (b.x * b.x + b.y * b.y) + (b.z * b.z + b.w * b.w);
                m1 = fmaxf(m1, fmaxf(fmaxf(b.x, b.y), fmaxf(b.z, b.w)));
                s2 += (c.x + c.y) + (c.z + c.w);
                q2 += (c.x * c.x + c.y * c.y) + (c.z * c.z + c.w * c.w);
                m2 = fmaxf(m2, fmaxf(fmaxf(c.x, c.y), fmaxf(c.z, c.w)));
                s3 += (d.x + d.y) + (d.z + d.w);
                q3 += (d.x * d.x + d.y * d.y) + (d.z * d.z + d.w * d.w);
                m3 = fmaxf(m3, fmaxf(fmaxf(d.x, d.y), fmaxf(d.z, d.w)));
            }
        }
    } else {
        for (int i = tid; i < n4; i += 256) {
            float4 a = x4[i];
            s0 += (a.x + a.y) + (a.z + a.w);
            q0 += (a.x * a.x + a.y * a.y) + (a.z * a.z + a.w * a.w);
            m0 = fmaxf(m0, fmaxf(fmaxf(a.x, a.y), fmaxf(a.z, a.w)));
        }
    }
    float s = (s0 + s1) + (s2 + s3);
    float q = (q0 + q1) + (q2 + q3);
    float mx = fmaxf(fmaxf(m0, m1), fmaxf(m2, m3));

    for (int off = 32; off > 0; off >>= 1) {
        s  += __shfl_down(s, off);
        q  += __shfl_down(q, off);
        mx  = fmaxf(mx, __shfl_down(mx, off));
    }
    __shared__ float ss[4], sq[4], sm[4];
    const int wid = tid >> 6, lane = tid & 63;
    if (lane == 0) { ss[wid] = s; sq[wid] = q; sm[wid] = mx; }
    __syncthreads();
    if (tid == 0) {
        float S = ss[0] + ss[1] + ss[2] + ss[3];
        float Q = sq[0] + sq[1] + sq[2] + sq[3];
        float M = fmaxf(fmaxf(sm[0], sm[1]), fmaxf(sm[2], sm[3]));
        float mean = S / (float)HW;
        float var  = (Q - S * mean) / (float)(HW - 1);  // unbiased (ddof=1)
        var = fmaxf(var, 0.f);
        float* up = u + (size_t)bc * 3;
        up[0] = mean;
        up[1] = M;
        up[2] = sqrtf(var);
    }
}

// One block per (b,c). Redundant per-block median (rank-select over u[b],
// 768 values) + own-channel gate, computed under the pre-issued x loads.
__global__ __launch_bounds__(256, 4) void gate_scale_kernel(
        const float* __restrict__ x,
        const float* __restrict__ u,      // [B][C][3]
        const float* __restrict__ w,      // [C][3]
        const float* __restrict__ gamma,
        const float* __restrict__ beta,
        const float* __restrict__ rmean,
        const float* __restrict__ rvar,
        float* __restrict__ out, int HW, int C) {
    const int bc  = blockIdx.x;
    const int b   = bc / C;
    const int c   = bc - b * C;
    const int tid = threadIdx.x;
    const int NV  = C * 3;  // 768
    const size_t base = (size_t)bc * (size_t)HW;
    const fvec4* __restrict__ x4 = (const fvec4*)(x + base);
    fvec4* __restrict__ o4 = (fvec4*)(out + base);
    const int n4 = HW >> 2;

    __shared__ float sv[768];
    __shared__ float ma, mb;

    if (n4 == 4096) {
        // 1) issue the block's 16 float4/thread x-loads first (in flight
        //    across the whole prologue)
        fvec4 r[16];
        #pragma unroll
        for (int k = 0; k < 16; ++k) r[k] = x4[tid + k * 256];

        // 2) stage u[b] (3 KiB, L2/L3-hot) + rank-select median of 768
        const float* ub = u + (size_t)b * NV;
        for (int i = tid; i < NV; i += 256) sv[i] = ub[i];
        __syncthreads();
        float v0 = sv[tid], v1 = sv[tid + 256], v2 = sv[tid + 512];
        int lt0 = 0, eq0 = 0, lt1 = 0, eq1 = 0, lt2 = 0, eq2 = 0;
        for (int i = 0; i < NV; ++i) {
            float o = sv[i];
            lt0 += (o < v0); eq0 += (o == v0);
            lt1 += (o < v1); eq1 += (o == v1);
            lt2 += (o < v2); eq2 += (o == v2);
        }
        const int r0 = (NV - 1) / 2;  // 383
        const int r1 = NV / 2;        // 384
        if (lt0 <= r0 && r0 < lt0 + eq0) ma = v0;
        if (lt1 <= r0 && r0 < lt1 + eq1) ma = v1;
        if (lt2 <= r0 && r0 < lt2 + eq2) ma = v2;
        if (lt0 <= r1 && r1 < lt0 + eq0) mb = v0;
        if (lt1 <= r1 && r1 < lt1 + eq1) mb = v1;
        if (lt2 <= r1 && r1 < lt2 + eq2) mb = v2;
        __syncthreads();
        const float med = 0.5f * (ma + mb);

        // 3) own channel's gate (all threads redundantly; wave-uniform)
        float z = 0.f;
        #pragma unroll
        for (int k = 0; k < 3; ++k) {
            float d = sv[c * 3 + k] - med;
            z += (d * d * d) * w[c * 3 + k];
        }
        z = (z - rmean[c]) * rsqrtf(rvar[c] + 1e-5f) * gamma[c] + beta[c];
        const float gv = 1.f / (1.f + expf(-z));

        // 4) multiply + nt-store
        #pragma unroll
        for (int k = 0; k < 16; ++k)
            __builtin_nontemporal_store(r[k] * gv, &o4[tid + k * 256]);
    } else {
        // generic fallback: median first, then stream
        const float* ub = u + (size_t)b * NV;
        for (int i = tid; i < NV; i += 256) sv[i] = ub[i];
        __syncthreads();
        float v0 = sv[tid], v1 = sv[tid + 256], v2 = sv[tid + 512];
        int lt0 = 0, eq0 = 0, lt1 = 0, eq1 = 0, lt2 = 0, eq2 = 0;
        for (int i = 0; i < NV; ++i) {
            float o = sv[i];
            lt0 += (o < v0); eq0 += (o == v0);
            lt1 += (o < v1); eq1 += (o == v1);
            lt2 += (o < v2); eq2 += (o == v2);
        }
        const int r0 = (NV - 1) / 2;
        const int r1 = NV / 2;
        if (lt0 <= r0 && r0 < lt0 + eq0) ma = v0;
        if (lt1 <= r0 && r0 < lt1 + eq1) ma = v1;
        if (lt2 <= r0 && r0 < lt2 + eq2) ma = v2;
        if (lt0 <= r1 && r1 < lt0 + eq0) mb = v0;
        if (lt1 <= r1 && r1 < lt1 + eq1) mb = v1;
        if (lt2 <= r1 && r1 < lt2 + eq2) mb = v2;
        __syncthreads();
        const float med = 0.5f * (ma + mb);
        float z = 0.f;
        #pragma unroll
        for (int k = 0; k < 3; ++k) {
            float d = sv[c * 3 + k] - med;
            z += (d * d * d) * w[c * 3 + k];
        }
        z = (z - rmean[c]) * rsqrtf(rvar[c] + 1e-5f) * gamma[c] + beta[c];
        const float gv = 1.f / (1.f + expf(-z));
        for (int i = tid; i < n4; i += 256) {
            fvec4 v = x4[i];
            __builtin_nontemporal_store(v * gv, &o4[i]);
        }
    }
}

extern "C" void kernel_launch(void* const* d_in, const int* in_sizes, int n_in,
                              void* d_out, int out_size, void* d_ws, size_t ws_size,
                              hipStream_t stream) {
    const float* x     = (const float*)d_in[0];
    const float* w     = (const float*)d_in[1];
    const float* gamma = (const float*)d_in[2];
    const float* beta  = (const float*)d_in[3];
    const float* rmean = (const float*)d_in[4];
    const float* rvar  = (const float*)d_in[5];
    float* out = (float*)d_out;

    const int C  = in_sizes[2];              // 256 (gamma)
    const int B  = 16;
    const int HW = in_sizes[0] / (B * C);    // 16384

    float* u = (float*)d_ws;                 // [B][C][3]

    stats_kernel<<<B * C, 256, 0, stream>>>(x, u, HW);
    gate_scale_kernel<<<B * C, 256, 0, stream>>>(x, u, w, gamma, beta, rmean,
                                                 rvar, out, HW, C);
}

// Round 9
// 195.154 us; speedup vs baseline: 1.6207x; 1.6207x over previous
//
#include <hip/hip_runtime.h>
#include <math.h>

// Shape: B=16, C=256, H=W=128, HW=16384. x = 256 MiB fp32 (== L3 size).
// Measured facts:
//  - Pass-2 x re-read gets ~50% L3 hits (R8: FETCH 128 MiB); stats runs
//    ~20 us (~13 TB/s) via cross-replay L3 residency of x.
//  - Device-scope atomic/fence fusion: catastrophic (+355 us).
//  - Redundant per-block median fusion: catastrophic (VALU-bound, +130 us).
//  - Scale kernel w/ nt-stores: only ~3 TB/s effective. THIS ROUND'S A/B:
//    plain stores in scale (everything else identical to the 160-us R7 config).
// Structure: 3 kernels.
//  K1 stats: per (b,c) block -> mean, max, std(ddof=1) -> u[B][C][3]
//  K2 median+gate: per batch -> rank-select median of 768 + conv/BN/sigmoid
//  K3 scale: per (b,c) block -> out = x * g[bc]; batch-8 loads, PLAIN stores.

typedef float fvec4 __attribute__((ext_vector_type(4)));

__global__ __launch_bounds__(256) void stats_kernel(
        const float* __restrict__ x, float* __restrict__ u, int HW) {
    const int bc  = blockIdx.x;
    const int tid = threadIdx.x;
    const float4* __restrict__ x4 =
        (const float4*)(x + (size_t)bc * (size_t)HW);
    const int n4 = HW >> 2;

    float s0 = 0.f, q0 = 0.f, m0 = -INFINITY;
    float s1 = 0.f, q1 = 0.f, m1 = -INFINITY;
    float s2 = 0.f, q2 = 0.f, m2 = -INFINITY;
    float s3 = 0.f, q3 = 0.f, m3 = -INFINITY;

    if (n4 == 4096) {
        #pragma unroll
        for (int half = 0; half < 2; ++half) {
            float4 r[8];
            const int bi = tid + half * 2048;
            #pragma unroll
            for (int k = 0; k < 8; ++k) r[k] = x4[bi + k * 256];
            #pragma unroll
            for (int k = 0; k < 8; k += 4) {
                float4 a = r[k], b = r[k + 1], c = r[k + 2], d = r[k + 3];
                s0 += (a.x + a.y) + (a.z + a.w);
                q0 += (a.x * a.x + a.y * a.y) + (a.z * a.z + a.w * a.w);
                m0 = fmaxf(m0, fmaxf(fmaxf(a.x, a.y), fmaxf(a.z, a.w)));
                s1 += (b.x + b.y) + (b.z + b.w);
                q1 += (b.x * b.x + b.y * b.y) + (b.z * b.z + b.w * b.w);
                m1 = fmaxf(m1, fmaxf(fmaxf(b.x, b.y), fmaxf(b.z, b.w)));
                s2 += (c.x + c.y) + (c.z + c.w);
                q2 += (c.x * c.x + c.y * c.y) + (c.z * c.z + c.w * c.w);
                m2 = fmaxf(m2, fmaxf(fmaxf(c.x, c.y), fmaxf(c.z, c.w)));
                s3 += (d.x + d.y) + (d.z + d.w);
                q3 += (d.x * d.x + d.y * d.y) + (d.z * d.z + d.w * d.w);
                m3 = fmaxf(m3, fmaxf(fmaxf(d.x, d.y), fmaxf(d.z, d.w)));
            }
        }
    } else {
        for (int i = tid; i < n4; i += 256) {
            float4 a = x4[i];
            s0 += (a.x + a.y) + (a.z + a.w);
            q0 += (a.x * a.x + a.y * a.y) + (a.z * a.z + a.w * a.w);
            m0 = fmaxf(m0, fmaxf(fmaxf(a.x, a.y), fmaxf(a.z, a.w)));
        }
    }
    float s = (s0 + s1) + (s2 + s3);
    float q = (q0 + q1) + (q2 + q3);
    float mx = fmaxf(fmaxf(m0, m1), fmaxf(m2, m3));

    for (int off = 32; off > 0; off >>= 1) {
        s  += __shfl_down(s, off);
        q  += __shfl_down(q, off);
        mx  = fmaxf(mx, __shfl_down(mx, off));
    }
    __shared__ float ss[4], sq[4], sm[4];
    const int wid = tid >> 6, lane = tid & 63;
    if (lane == 0) { ss[wid] = s; sq[wid] = q; sm[wid] = mx; }
    __syncthreads();
    if (tid == 0) {
        float S = ss[0] + ss[1] + ss[2] + ss[3];
        float Q = sq[0] + sq[1] + sq[2] + sq[3];
        float M = fmaxf(fmaxf(sm[0], sm[1]), fmaxf(sm[2], sm[3]));
        float mean = S / (float)HW;
        float var  = (Q - S * mean) / (float)(HW - 1);  // unbiased (ddof=1)
        var = fmaxf(var, 0.f);
        float* up = u + (size_t)bc * 3;
        up[0] = mean;
        up[1] = M;
        up[2] = sqrtf(var);
    }
}

// One block per batch. NV = C*3 = 768; median = mean of ranks 383,384.
__global__ void median_gate_kernel(const float* __restrict__ u,
                                   const float* __restrict__ w,
                                   const float* __restrict__ gamma,
                                   const float* __restrict__ beta,
                                   const float* __restrict__ rmean,
                                   const float* __restrict__ rvar,
                                   float* __restrict__ g, int C) {
    const int b   = blockIdx.x;
    const int tid = threadIdx.x;
    const int NV  = C * 3;  // 768
    __shared__ float sv[768];
    __shared__ float ma, mb;

    const float* ub = u + (size_t)b * NV;
    for (int i = tid; i < NV; i += 256) sv[i] = ub[i];
    __syncthreads();

    float v0 = sv[tid], v1 = sv[tid + 256], v2 = sv[tid + 512];
    int lt0 = 0, eq0 = 0, lt1 = 0, eq1 = 0, lt2 = 0, eq2 = 0;
    for (int i = 0; i < NV; ++i) {
        float o = sv[i];
        lt0 += (o < v0); eq0 += (o == v0);
        lt1 += (o < v1); eq1 += (o == v1);
        lt2 += (o < v2); eq2 += (o == v2);
    }
    const int r0 = (NV - 1) / 2;  // 383
    const int r1 = NV / 2;        // 384
    if (lt0 <= r0 && r0 < lt0 + eq0) ma = v0;
    if (lt1 <= r0 && r0 < lt1 + eq1) ma = v1;
    if (lt2 <= r0 && r0 < lt2 + eq2) ma = v2;
    if (lt0 <= r1 && r1 < lt0 + eq0) mb = v0;
    if (lt1 <= r1 && r1 < lt1 + eq1) mb = v1;
    if (lt2 <= r1 && r1 < lt2 + eq2) mb = v2;
    __syncthreads();

    const float med = 0.5f * (ma + mb);
    if (tid < C) {
        const int c = tid;
        float z = 0.f;
        #pragma unroll
        for (int k = 0; k < 3; ++k) {
            float d = sv[c * 3 + k] - med;
            z += (d * d * d) * w[c * 3 + k];
        }
        z = (z - rmean[c]) * rsqrtf(rvar[c] + 1e-5f) * gamma[c] + beta[c];
        g[(size_t)b * C + c] = 1.f / (1.f + expf(-z));
    }
}

// One block per (b,c); g wave-uniform; batch-8 loads + PLAIN stores (A/B vs nt).
__global__ __launch_bounds__(256) void scale_kernel(
        const float* __restrict__ x, const float* __restrict__ g,
        float* __restrict__ out, int HW) {
    const int bc = blockIdx.x;
    const float gv = g[bc];
    const size_t base = (size_t)bc * (size_t)HW;
    const fvec4* __restrict__ x4 = (const fvec4*)(x + base);
    fvec4* __restrict__ o4 = (fvec4*)(out + base);
    const int n4 = HW >> 2;
    if (n4 == 4096) {
        #pragma unroll
        for (int half = 0; half < 2; ++half) {
            const int bi = (int)threadIdx.x + half * 2048;
            fvec4 r[8];
            #pragma unroll
            for (int k = 0; k < 8; ++k)
                r[k] = x4[bi + k * 256];
            #pragma unroll
            for (int k = 0; k < 8; ++k)
                o4[bi + k * 256] = r[k] * gv;
        }
    } else {
        for (int i = threadIdx.x; i < n4; i += 256) {
            fvec4 v = x4[i];
            o4[i] = v * gv;
        }
    }
}

extern "C" void kernel_launch(void* const* d_in, const int* in_sizes, int n_in,
                              void* d_out, int out_size, void* d_ws, size_t ws_size,
                              hipStream_t stream) {
    const float* x     = (const float*)d_in[0];
    const float* w     = (const float*)d_in[1];
    const float* gamma = (const float*)d_in[2];
    const float* beta  = (const float*)d_in[3];
    const float* rmean = (const float*)d_in[4];
    const float* rvar  = (const float*)d_in[5];
    float* out = (float*)d_out;

    const int C  = in_sizes[2];              // 256 (gamma)
    const int B  = 16;
    const int HW = in_sizes[0] / (B * C);    // 16384

    float* u = (float*)d_ws;                 // [B][C][3]
    float* g = u + (size_t)B * C * 3;        // [B][C]

    stats_kernel<<<B * C, 256, 0, stream>>>(x, u, HW);
    median_gate_kernel<<<B, 256, 0, stream>>>(u, w, gamma, beta, rmean, rvar, g, C);
    scale_kernel<<<B * C, 256, 0, stream>>>(x, g, out, HW);
}

// Round 10
// 161.878 us; speedup vs baseline: 1.9539x; 1.2056x over previous
//
#include <hip/hip_runtime.h>
#include <math.h>

// Shape: B=16, C=256, H=W=128, HW=16384. x = 256 MiB fp32 (== L3 size).
// Cache model (measured R8/R9): L3 holds exactly ONE of {x, out}.
//  - Regime A (nt-stores, x semi-resident): 160 us.
//  - Regime B wrong (plain stores + plain loads): 195 us (thrash).
//  - THIS ROUND — Regime B right: nt-LOADS for x everywhere (x never
//    allocates L3) + PLAIN stores (out owns L3, writes absorbed in place,
//    HBM write traffic ~0 at steady state).
// Structure: 3 kernels.
//  K1 stats: per (b,c) block -> mean, max, std(ddof=1) -> u[B][C][3]
//  K2 median+gate: per batch -> rank-select median of 768 + conv/BN/sigmoid
//  K3 scale: per (b,c) block -> out = x * g[bc]; nt loads, plain stores.

typedef float fvec4 __attribute__((ext_vector_type(4)));

__global__ __launch_bounds__(256) void stats_kernel(
        const float* __restrict__ x, float* __restrict__ u, int HW) {
    const int bc  = blockIdx.x;
    const int tid = threadIdx.x;
    const fvec4* __restrict__ x4 =
        (const fvec4*)(x + (size_t)bc * (size_t)HW);
    const int n4 = HW >> 2;

    float s0 = 0.f, q0 = 0.f, m0 = -INFINITY;
    float s1 = 0.f, q1 = 0.f, m1 = -INFINITY;
    float s2 = 0.f, q2 = 0.f, m2 = -INFINITY;
    float s3 = 0.f, q3 = 0.f, m3 = -INFINITY;

    if (n4 == 4096) {
        #pragma unroll
        for (int half = 0; half < 2; ++half) {
            fvec4 r[8];
            const int bi = tid + half * 2048;
            #pragma unroll
            for (int k = 0; k < 8; ++k)
                r[k] = __builtin_nontemporal_load(&x4[bi + k * 256]);
            #pragma unroll
            for (int k = 0; k < 8; k += 4) {
                fvec4 a = r[k], b = r[k + 1], c = r[k + 2], d = r[k + 3];
                s0 += (a[0] + a[1]) + (a[2] + a[3]);
                q0 += (a[0] * a[0] + a[1] * a[1]) + (a[2] * a[2] + a[3] * a[3]);
                m0 = fmaxf(m0, fmaxf(fmaxf(a[0], a[1]), fmaxf(a[2], a[3])));
                s1 += (b[0] + b[1]) + (b[2] + b[3]);
                q1 += (b[0] * b[0] + b[1] * b[1]) + (b[2] * b[2] + b[3] * b[3]);
                m1 = fmaxf(m1, fmaxf(fmaxf(b[0], b[1]), fmaxf(b[2], b[3])));
                s2 += (c[0] + c[1]) + (c[2] + c[3]);
                q2 += (c[0] * c[0] + c[1] * c[1]) + (c[2] * c[2] + c[3] * c[3]);
                m2 = fmaxf(m2, fmaxf(fmaxf(c[0], c[1]), fmaxf(c[2], c[3])));
                s3 += (d[0] + d[1]) + (d[2] + d[3]);
                q3 += (d[0] * d[0] + d[1] * d[1]) + (d[2] * d[2] + d[3] * d[3]);
                m3 = fmaxf(m3, fmaxf(fmaxf(d[0], d[1]), fmaxf(d[2], d[3])));
            }
        }
    } else {
        for (int i = tid; i < n4; i += 256) {
            fvec4 a = __builtin_nontemporal_load(&x4[i]);
            s0 += (a[0] + a[1]) + (a[2] + a[3]);
            q0 += (a[0] * a[0] + a[1] * a[1]) + (a[2] * a[2] + a[3] * a[3]);
            m0 = fmaxf(m0, fmaxf(fmaxf(a[0], a[1]), fmaxf(a[2], a[3])));
        }
    }
    float s = (s0 + s1) + (s2 + s3);
    float q = (q0 + q1) + (q2 + q3);
    float mx = fmaxf(fmaxf(m0, m1), fmaxf(m2, m3));

    for (int off = 32; off > 0; off >>= 1) {
        s  += __shfl_down(s, off);
        q  += __shfl_down(q, off);
        mx  = fmaxf(mx, __shfl_down(mx, off));
    }
    __shared__ float ss[4], sq[4], sm[4];
    const int wid = tid >> 6, lane = tid & 63;
    if (lane == 0) { ss[wid] = s; sq[wid] = q; sm[wid] = mx; }
    __syncthreads();
    if (tid == 0) {
        float S = ss[0] + ss[1] + ss[2] + ss[3];
        float Q = sq[0] + sq[1] + sq[2] + sq[3];
        float M = fmaxf(fmaxf(sm[0], sm[1]), fmaxf(sm[2], sm[3]));
        float mean = S / (float)HW;
        float var  = (Q - S * mean) / (float)(HW - 1);  // unbiased (ddof=1)
        var = fmaxf(var, 0.f);
        float* up = u + (size_t)bc * 3;
        up[0] = mean;
        up[1] = M;
        up[2] = sqrtf(var);
    }
}

// One block per batch. NV = C*3 = 768; median = mean of ranks 383,384.
__global__ void median_gate_kernel(const float* __restrict__ u,
                                   const float* __restrict__ w,
                                   const float* __restrict__ gamma,
                                   const float* __restrict__ beta,
                                   const float* __restrict__ rmean,
                                   const float* __restrict__ rvar,
                                   float* __restrict__ g, int C) {
    const int b   = blockIdx.x;
    const int tid = threadIdx.x;
    const int NV  = C * 3;  // 768
    __shared__ float sv[768];
    __shared__ float ma, mb;

    const float* ub = u + (size_t)b * NV;
    for (int i = tid; i < NV; i += 256) sv[i] = ub[i];
    __syncthreads();

    float v0 = sv[tid], v1 = sv[tid + 256], v2 = sv[tid + 512];
    int lt0 = 0, eq0 = 0, lt1 = 0, eq1 = 0, lt2 = 0, eq2 = 0;
    for (int i = 0; i < NV; ++i) {
        float o = sv[i];
        lt0 += (o < v0); eq0 += (o == v0);
        lt1 += (o < v1); eq1 += (o == v1);
        lt2 += (o < v2); eq2 += (o == v2);
    }
    const int r0 = (NV - 1) / 2;  // 383
    const int r1 = NV / 2;        // 384
    if (lt0 <= r0 && r0 < lt0 + eq0) ma = v0;
    if (lt1 <= r0 && r0 < lt1 + eq1) ma = v1;
    if (lt2 <= r0 && r0 < lt2 + eq2) ma = v2;
    if (lt0 <= r1 && r1 < lt0 + eq0) mb = v0;
    if (lt1 <= r1 && r1 < lt1 + eq1) mb = v1;
    if (lt2 <= r1 && r1 < lt2 + eq2) mb = v2;
    __syncthreads();

    const float med = 0.5f * (ma + mb);
    if (tid < C) {
        const int c = tid;
        float z = 0.f;
        #pragma unroll
        for (int k = 0; k < 3; ++k) {
            float d = sv[c * 3 + k] - med;
            z += (d * d * d) * w[c * 3 + k];
        }
        z = (z - rmean[c]) * rsqrtf(rvar[c] + 1e-5f) * gamma[c] + beta[c];
        g[(size_t)b * C + c] = 1.f / (1.f + expf(-z));
    }
}

// One block per (b,c); g wave-uniform; nt loads (protect out's L3 residency),
// PLAIN stores (out owns L3; repeated re-dirty absorbs HBM write traffic).
__global__ __launch_bounds__(256) void scale_kernel(
        const float* __restrict__ x, const float* __restrict__ g,
        float* __restrict__ out, int HW) {
    const int bc = blockIdx.x;
    const float gv = g[bc];
    const size_t base = (size_t)bc * (size_t)HW;
    const fvec4* __restrict__ x4 = (const fvec4*)(x + base);
    fvec4* __restrict__ o4 = (fvec4*)(out + base);
    const int n4 = HW >> 2;
    if (n4 == 4096) {
        #pragma unroll
        for (int half = 0; half < 2; ++half) {
            const int bi = (int)threadIdx.x + half * 2048;
            fvec4 r[8];
            #pragma unroll
            for (int k = 0; k < 8; ++k)
                r[k] = __builtin_nontemporal_load(&x4[bi + k * 256]);
            #pragma unroll
            for (int k = 0; k < 8; ++k)
                o4[bi + k * 256] = r[k] * gv;
        }
    } else {
        for (int i = threadIdx.x; i < n4; i += 256) {
            fvec4 v = __builtin_nontemporal_load(&x4[i]);
            o4[i] = v * gv;
        }
    }
}

extern "C" void kernel_launch(void* const* d_in, const int* in_sizes, int n_in,
                              void* d_out, int out_size, void* d_ws, size_t ws_size,
                              hipStream_t stream) {
    const float* x     = (const float*)d_in[0];
    const float* w     = (const float*)d_in[1];
    const float* gamma = (const float*)d_in[2];
    const float* beta  = (const float*)d_in[3];
    const float* rmean = (const float*)d_in[4];
    const float* rvar  = (const float*)d_in[5];
    float* out = (float*)d_out;

    const int C  = in_sizes[2];              // 256 (gamma)
    const int B  = 16;
    const int HW = in_sizes[0] / (B * C);    // 16384

    float* u = (float*)d_ws;                 // [B][C][3]
    float* g = u + (size_t)B * C * 3;        // [B][C]

    stats_kernel<<<B * C, 256, 0, stream>>>(x, u, HW);
    median_gate_kernel<<<B, 256, 0, stream>>>(u, w, gamma, beta, rmean, rvar, g, C);
    scale_kernel<<<B * C, 256, 0, stream>>>(x, g, out, HW);
}

// Round 11
// 161.242 us; speedup vs baseline: 1.9616x; 1.0039x over previous
//
#include <hip/hip_runtime.h>
#include <math.h>

// Shape: B=16, C=256, H=W=128, HW=16384. x = 256 MiB fp32 (== L3 size).
// Measured config matrix (R3-R10): all cache policies (nt/plain in any slot)
// = 160±2 us except all-plain = 195. L3 policy is NOT the lever.
// Decomposition: stats ~20 (L3-hot), median ~4, gaps ~6, scale ~130 us
// (~3 TB/s for 384 MiB HBM) — scale is the anomaly vs 6.3 TB/s copy ubench.
// THIS ROUND: scale via global_load_lds DMA double-buffer (counted vmcnt(4),
// raw s_barrier) — removes the VGPR load->store round-trip dependency that
// forces per-wave store drains between read batches.

typedef float fvec4 __attribute__((ext_vector_type(4)));

__global__ __launch_bounds__(256) void stats_kernel(
        const float* __restrict__ x, float* __restrict__ u, int HW) {
    const int bc  = blockIdx.x;
    const int tid = threadIdx.x;
    const float4* __restrict__ x4 =
        (const float4*)(x + (size_t)bc * (size_t)HW);
    const int n4 = HW >> 2;

    float s0 = 0.f, q0 = 0.f, m0 = -INFINITY;
    float s1 = 0.f, q1 = 0.f, m1 = -INFINITY;
    float s2 = 0.f, q2 = 0.f, m2 = -INFINITY;
    float s3 = 0.f, q3 = 0.f, m3 = -INFINITY;

    if (n4 == 4096) {
        #pragma unroll
        for (int half = 0; half < 2; ++half) {
            float4 r[8];
            const int bi = tid + half * 2048;
            #pragma unroll
            for (int k = 0; k < 8; ++k) r[k] = x4[bi + k * 256];
            #pragma unroll
            for (int k = 0; k < 8; k += 4) {
                float4 a = r[k], b = r[k + 1], c = r[k + 2], d = r[k + 3];
                s0 += (a.x + a.y) + (a.z + a.w);
                q0 += (a.x * a.x + a.y * a.y) + (a.z * a.z + a.w * a.w);
                m0 = fmaxf(m0, fmaxf(fmaxf(a.x, a.y), fmaxf(a.z, a.w)));
                s1 += (b.x + b.y) + (b.z + b.w);
                q1 += (b.x * b.x + b.y * b.y) + (b.z * b.z + b.w * b.w);
                m1 = fmaxf(m1, fmaxf(fmaxf(b.x, b.y), fmaxf(b.z, b.w)));
                s2 += (c.x + c.y) + (c.z + c.w);
                q2 += (c.x * c.x + c.y * c.y) + (c.z * c.z + c.w * c.w);
                m2 = fmaxf(m2, fmaxf(fmaxf(c.x, c.y), fmaxf(c.z, c.w)));
                s3 += (d.x + d.y) + (d.z + d.w);
                q3 += (d.x * d.x + d.y * d.y) + (d.z * d.z + d.w * d.w);
                m3 = fmaxf(m3, fmaxf(fmaxf(d.x, d.y), fmaxf(d.z, d.w)));
            }
        }
    } else {
        for (int i = tid; i < n4; i += 256) {
            float4 a = x4[i];
            s0 += (a.x + a.y) + (a.z + a.w);
            q0 += (a.x * a.x + a.y * a.y) + (a.z * a.z + a.w * a.w);
            m0 = fmaxf(m0, fmaxf(fmaxf(a.x, a.y), fmaxf(a.z, a.w)));
        }
    }
    float s = (s0 + s1) + (s2 + s3);
    float q = (q0 + q1) + (q2 + q3);
    float mx = fmaxf(fmaxf(m0, m1), fmaxf(m2, m3));

    for (int off = 32; off > 0; off >>= 1) {
        s  += __shfl_down(s, off);
        q  += __shfl_down(q, off);
        mx  = fmaxf(mx, __shfl_down(mx, off));
    }
    __shared__ float ss[4], sq[4], sm[4];
    const int wid = tid >> 6, lane = tid & 63;
    if (lane == 0) { ss[wid] = s; sq[wid] = q; sm[wid] = mx; }
    __syncthreads();
    if (tid == 0) {
        float S = ss[0] + ss[1] + ss[2] + ss[3];
        float Q = sq[0] + sq[1] + sq[2] + sq[3];
        float M = fmaxf(fmaxf(sm[0], sm[1]), fmaxf(sm[2], sm[3]));
        float mean = S / (float)HW;
        float var  = (Q - S * mean) / (float)(HW - 1);  // unbiased (ddof=1)
        var = fmaxf(var, 0.f);
        float* up = u + (size_t)bc * 3;
        up[0] = mean;
        up[1] = M;
        up[2] = sqrtf(var);
    }
}

// One block per batch. NV = C*3 = 768; median = mean of ranks 383,384.
__global__ void median_gate_kernel(const float* __restrict__ u,
                                   const float* __restrict__ w,
                                   const float* __restrict__ gamma,
                                   const float* __restrict__ beta,
                                   const float* __restrict__ rmean,
                                   const float* __restrict__ rvar,
                                   float* __restrict__ g, int C) {
    const int b   = blockIdx.x;
    const int tid = threadIdx.x;
    const int NV  = C * 3;  // 768
    __shared__ float sv[768];
    __shared__ float ma, mb;

    const float* ub = u + (size_t)b * NV;
    for (int i = tid; i < NV; i += 256) sv[i] = ub[i];
    __syncthreads();

    float v0 = sv[tid], v1 = sv[tid + 256], v2 = sv[tid + 512];
    int lt0 = 0, eq0 = 0, lt1 = 0, eq1 = 0, lt2 = 0, eq2 = 0;
    for (int i = 0; i < NV; ++i) {
        float o = sv[i];
        lt0 += (o < v0); eq0 += (o == v0);
        lt1 += (o < v1); eq1 += (o == v1);
        lt2 += (o < v2); eq2 += (o == v2);
    }
    const int r0 = (NV - 1) / 2;  // 383
    const int r1 = NV / 2;        // 384
    if (lt0 <= r0 && r0 < lt0 + eq0) ma = v0;
    if (lt1 <= r0 && r0 < lt1 + eq1) ma = v1;
    if (lt2 <= r0 && r0 < lt2 + eq2) ma = v2;
    if (lt0 <= r1 && r1 < lt0 + eq0) mb = v0;
    if (lt1 <= r1 && r1 < lt1 + eq1) mb = v1;
    if (lt2 <= r1 && r1 < lt2 + eq2) mb = v2;
    __syncthreads();

    const float med = 0.5f * (ma + mb);
    if (tid < C) {
        const int c = tid;
        float z = 0.f;
        #pragma unroll
        for (int k = 0; k < 3; ++k) {
            float d = sv[c * 3 + k] - med;
            z += (d * d * d) * w[c * 3 + k];
        }
        z = (z - rmean[c]) * rsqrtf(rvar[c] + 1e-5f) * gamma[c] + beta[c];
        g[(size_t)b * C + c] = 1.f / (1.f + expf(-z));
    }
}

// Scale via DMA: global_load_lds double-buffer, 16 KiB chunks.
// Per chunk: stage next chunk's DMA (stays in flight across the barrier via
// counted vmcnt(4)), raw s_barrier, ds_read + mul + nt-store current chunk.
__global__ __launch_bounds__(256) void scale_kernel(
        const float* __restrict__ x, const float* __restrict__ g,
        float* __restrict__ out, int HW) {
    const int bc  = blockIdx.x;
    const int tid = threadIdx.x;
    const float gv = g[bc];
    const size_t base = (size_t)bc * (size_t)HW;
    const fvec4* __restrict__ x4 = (const fvec4*)(x + base);
    fvec4* __restrict__ o4 = (fvec4*)(out + base);
    const int n4 = HW >> 2;

    if ((n4 & 1023) == 0) {
        __shared__ fvec4 sbuf[2][1024];   // 2 x 16 KiB
        const int w    = tid >> 6;        // wave 0..3
        const int lane = tid & 63;
        const int nch  = n4 >> 10;        // 4 chunks of 1024 float4

        // prologue: stage chunk 0 -> buf 0 (4 DMA ops per wave, 1 KiB each)
        #pragma unroll
        for (int j = 0; j < 4; ++j) {
            const int seg = j * 4 + w;    // 16 segments of 64 float4
            __builtin_amdgcn_global_load_lds(
                (const __attribute__((address_space(1))) void*)&x4[seg * 64 + lane],
                (__attribute__((address_space(3))) void*)&sbuf[0][seg * 64],
                16, 0, 0);
        }
        for (int c = 0; c < nch; ++c) {
            const int cur = c & 1;
            if (c + 1 < nch) {
                // stage next chunk into the other buffer
                #pragma unroll
                for (int j = 0; j < 4; ++j) {
                    const int seg = j * 4 + w;
                    __builtin_amdgcn_global_load_lds(
                        (const __attribute__((address_space(1))) void*)
                            &x4[(c + 1) * 1024 + seg * 64 + lane],
                        (__attribute__((address_space(3))) void*)
                            &sbuf[cur ^ 1][seg * 64],
                        16, 0, 0);
                }
                // wait: all but the 4 newest (= next chunk's DMA) retired.
                // Guarantees chunk c's DMA landed + prior stores drained,
                // while chunk c+1's DMA stays in flight across the barrier.
                asm volatile("s_waitcnt vmcnt(4)" ::: "memory");
            } else {
                asm volatile("s_waitcnt vmcnt(0)" ::: "memory");
            }
            __builtin_amdgcn_s_barrier();
            #pragma unroll
            for (int j = 0; j < 4; ++j) {
                fvec4 v = sbuf[cur][tid + j * 256];
                __builtin_nontemporal_store(v * gv, &o4[c * 1024 + j * 256 + tid]);
            }
            // all ds_reads complete (stores depend on them -> lgkm waited);
            // barrier protects buf[cur] before next iteration's DMA overwrite
            __builtin_amdgcn_s_barrier();
        }
    } else {
        for (int i = tid; i < n4; i += 256) {
            fvec4 v = x4[i];
            __builtin_nontemporal_store(v * gv, &o4[i]);
        }
    }
}

extern "C" void kernel_launch(void* const* d_in, const int* in_sizes, int n_in,
                              void* d_out, int out_size, void* d_ws, size_t ws_size,
                              hipStream_t stream) {
    const float* x     = (const float*)d_in[0];
    const float* w     = (const float*)d_in[1];
    const float* gamma = (const float*)d_in[2];
    const float* beta  = (const float*)d_in[3];
    const float* rmean = (const float*)d_in[4];
    const float* rvar  = (const float*)d_in[5];
    float* out = (float*)d_out;

    const int C  = in_sizes[2];              // 256 (gamma)
    const int B  = 16;
    const int HW = in_sizes[0] / (B * C);    // 16384

    float* u = (float*)d_ws;                 // [B][C][3]
    float* g = u + (size_t)B * C * 3;        // [B][C]

    stats_kernel<<<B * C, 256, 0, stream>>>(x, u, HW);
    median_gate_kernel<<<B, 256, 0, stream>>>(u, w, gamma, beta, rmean, rvar, g, C);
    scale_kernel<<<B * C, 256, 0, stream>>>(x, g, out, HW);
}